// Round 9
// baseline (234.866 us; speedup 1.0000x reference)
//
#include <hip/hip_runtime.h>

// Problem constants: N=50000 nodes, E=800000 edges, IN_F=H_F=128, OUT_F=3.
#define NN   50000
#define NE   800000
#define FH   128
#define NOUT 3
#define BN_EPS 1e-5f

#define CAP  64            // bucket capacity per node; in-deg ~ Poisson(16),
                           // P(deg>=64) ~ 1e-18/node -- safe
#define EWS  65535.0f      // 16-bit fixed-point scale for edge weights
#define IEWS (1.0f / 65535.0f)

#define GEMM_BLKS   3125          // NN/16
#define BUCKET_BLKS 625           // x 256 thr x 5 edges = 800000 exactly
#define FUSED_BLKS  3750          // every 6th block (%6==5) is bucket

// Workspace layout (float-sized slots). Total ~9.75M floats = 39 MB.
#define WS_H2     0           // h*dinv packed bf16x2, uint[NN*64]
#define WS_AGG2   3200000     // relu out packed bf16x2 uint[NN*64]
#define WS_BUCKET 6400000     // uint[NN*CAP] (src<<16 | ew16)  [3200000]
#define WS_CNT    9600000     // int[NN] bucket counts
#define WS_DINV   9650000     // float[NN]
#define WS_SUMS   9700000     // sum[128], sumsq[128]
#define WS_PREP   9700256     // wmod[128*3], bias_out[3]

// round-to-nearest-even bf16 packing of two floats -> uint (lo=a, hi=b)
__device__ __forceinline__ unsigned int pack_bf16(float a, float b) {
    unsigned int ua = __float_as_uint(a);
    unsigned int ub = __float_as_uint(b);
    ua += 0x7fffu + ((ua >> 16) & 1u);
    ub += 0x7fffu + ((ub >> 16) & 1u);
    return (ua >> 16) | (ub & 0xffff0000u);
}
__device__ __forceinline__ float bf16_lo(unsigned int u) {
    return __uint_as_float(u << 16);
}
__device__ __forceinline__ float bf16_hi(unsigned int u) {
    return __uint_as_float(u & 0xffff0000u);
}

#define FMA4(acc, a, w0, w1, w2, w3)                                          \
    acc.x = fmaf(a.x, w0.x, fmaf(a.y, w1.x, fmaf(a.z, w2.x, fmaf(a.w, w3.x, acc.x)))); \
    acc.y = fmaf(a.x, w0.y, fmaf(a.y, w1.y, fmaf(a.z, w2.y, fmaf(a.w, w3.y, acc.y)))); \
    acc.z = fmaf(a.x, w0.z, fmaf(a.y, w1.z, fmaf(a.z, w2.z, fmaf(a.w, w3.z, acc.z)))); \
    acc.w = fmaf(a.x, w0.w, fmaf(a.y, w1.w, fmaf(a.z, w2.w, fmaf(a.w, w3.w, acc.w))));

// ---------------------------------------------------------------------------
// K1: FUSED gemm + bucket, interleaved (blockIdx%6==5 -> bucket). Bucket
// threads batch 5 edges in separated phases (loads, 5 independent atomics,
// stores). Gemm stages conv_w in 4x 32-row LDS chunks (16 KB).
// ---------------------------------------------------------------------------
__global__ __launch_bounds__(256) void k_gemm_bucket(
        const float* __restrict__ x, const float* __restrict__ w,
        unsigned int* __restrict__ h2,
        const int* __restrict__ ei, const float* __restrict__ ew,
        int* __restrict__ cnt, unsigned int* __restrict__ bucket) {
    __shared__ float sw[32 * FH];  // 16 KB
    if ((blockIdx.x % 6) != 5) {
        const int gblk = blockIdx.x - blockIdx.x / 6;  // 0..3124
        const int j  = (threadIdx.x & 31) * 4;         // feature base
        const int p  = threadIdx.x >> 5;
        const int n0 = gblk * 16 + p * 2;

        const float4* x0 = (const float4*)(x + (size_t)n0 * FH);
        const float4* x1 = (const float4*)(x + (size_t)(n0 + 1) * FH);
        float4 acc0 = {0.f, 0.f, 0.f, 0.f};
        float4 acc1 = {0.f, 0.f, 0.f, 0.f};

        for (int c = 0; c < 4; ++c) {
            const float4* w4 = (const float4*)(w + (size_t)c * 32 * FH);
            float4* s4 = (float4*)sw;
#pragma unroll
            for (int i = 0; i < 4; ++i)
                s4[threadIdx.x + i * 256] = w4[threadIdx.x + i * 256];
            __syncthreads();
#pragma unroll
            for (int k4 = 0; k4 < 8; ++k4) {
                float4 a0 = x0[c * 8 + k4];
                float4 a1 = x1[c * 8 + k4];
                const float* wr = &sw[(k4 * 4) * FH + j];
                float4 w0 = *(const float4*)(wr);
                float4 w1 = *(const float4*)(wr + FH);
                float4 w2 = *(const float4*)(wr + 2 * FH);
                float4 w3 = *(const float4*)(wr + 3 * FH);
                FMA4(acc0, a0, w0, w1, w2, w3);
                FMA4(acc1, a1, w0, w1, w2, w3);
            }
            __syncthreads();
        }
        uint2 o0, o1;
        o0.x = pack_bf16(acc0.x, acc0.y);  o0.y = pack_bf16(acc0.z, acc0.w);
        o1.x = pack_bf16(acc1.x, acc1.y);  o1.y = pack_bf16(acc1.z, acc1.w);
        *(uint2*)(h2 + (size_t)n0 * 64 + (j >> 1))       = o0;
        *(uint2*)(h2 + (size_t)(n0 + 1) * 64 + (j >> 1)) = o1;
    } else {
        const int bidx = blockIdx.x / 6;                   // 0..624
        const int e0   = bidx * 1280 + threadIdx.x;        // +k*256, k<5
        int          col[5];
        unsigned int ent[5];
#pragma unroll
        for (int k = 0; k < 5; ++k) {
            int e  = e0 + k * 256;
            int row = ei[e];
            col[k] = ei[NE + e];
            ent[k] = ((unsigned int)row << 16) | __float2uint_rn(ew[e] * EWS);
        }
        int slot[5];
#pragma unroll
        for (int k = 0; k < 5; ++k) slot[k] = atomicAdd(&cnt[col[k]], 1);
#pragma unroll
        for (int k = 0; k < 5; ++k)
            bucket[(size_t)col[k] * CAP + slot[k]] = ent[k];
    }
}

// ---------------------------------------------------------------------------
// K2: per node: deg -> dinv; rescale h2 row in place: hs = h * dinv.
// After this, gather needs NO per-src dinv load:
//   agg[n] = dinv[n] * ( sum_e ew_e * hs[src_e] + hs[n] )
// ---------------------------------------------------------------------------
__global__ __launch_bounds__(256) void k_degdinv(unsigned int* __restrict__ h2,
                                                 const unsigned int* __restrict__ bucket,
                                                 const int* __restrict__ cnt,
                                                 float* __restrict__ dinv) {
    int n = blockIdx.x * 4 + (threadIdx.x >> 6);  // 12500 blocks exactly
    int lane = threadIdx.x & 63;
    int c = cnt[n];
    unsigned int v = (lane < c) ? (bucket[(size_t)n * CAP + lane] & 0xffffu) : 0u;
#pragma unroll
    for (int off = 32; off > 0; off >>= 1) v += __shfl_xor(v, off, 64);
    float dv = rsqrtf((float)v * IEWS + 1.0f);  // +1 = self loop
    if (lane == 0) dinv[n] = dv;
    unsigned int hv = h2[(size_t)n * 64 + lane];
    h2[(size_t)n * 64 + lane] = pack_bf16(bf16_lo(hv) * dv, bf16_hi(hv) * dv);
}

// ---------------------------------------------------------------------------
// K3: gather-aggregate. One wave per node; lane owns feature pair.
// Inner loop: bucket uint4 load -> 8 independent hs-row loads; t = ew only.
// ---------------------------------------------------------------------------
__global__ __launch_bounds__(256) void k_gather(const unsigned int* __restrict__ h2,
                                                const float* __restrict__ dinv,
                                                const unsigned int* __restrict__ bucket,
                                                const int* __restrict__ cnt,
                                                const float* __restrict__ conv_b,
                                                unsigned int* __restrict__ agg2) {
    int n = blockIdx.x * 4 + (threadIdx.x >> 6);  // 12500 blocks exactly
    int lane = threadIdx.x & 63;

    float dvn = dinv[n];
    unsigned int hself = h2[(size_t)n * 64 + lane];  // already h*dinv
    float ax = bf16_lo(hself);
    float ay = bf16_hi(hself);

    const unsigned int* bkt = bucket + (size_t)n * CAP;
    int c = cnt[n];
    int j = 0;
    for (; j + 8 <= c; j += 8) {
        uint4 b0 = *(const uint4*)(bkt + j);
        uint4 b1 = *(const uint4*)(bkt + j + 4);
        unsigned int u[8] = {b0.x, b0.y, b0.z, b0.w, b1.x, b1.y, b1.z, b1.w};
        float t[8];
        unsigned int q[8];
#pragma unroll
        for (int r = 0; r < 8; ++r) {
            t[r] = (float)(u[r] & 0xffffu) * IEWS;
            q[r] = h2[(size_t)(u[r] >> 16) * 64 + lane];
        }
#pragma unroll
        for (int r = 0; r < 8; ++r) {
            ax = fmaf(bf16_lo(q[r]), t[r], ax);
            ay = fmaf(bf16_hi(q[r]), t[r], ay);
        }
    }
    if (j + 4 <= c) {
        uint4 b0 = *(const uint4*)(bkt + j);
        unsigned int u[4] = {b0.x, b0.y, b0.z, b0.w};
#pragma unroll
        for (int r = 0; r < 4; ++r) {
            float t = (float)(u[r] & 0xffffu) * IEWS;
            unsigned int q = h2[(size_t)(u[r] >> 16) * 64 + lane];
            ax = fmaf(bf16_lo(q), t, ax);
            ay = fmaf(bf16_hi(q), t, ay);
        }
        j += 4;
    }
    for (; j < c; ++j) {
        unsigned int u0 = bkt[j];
        float t0 = (float)(u0 & 0xffffu) * IEWS;
        unsigned int q0 = h2[(size_t)(u0 >> 16) * 64 + lane];
        ax = fmaf(bf16_lo(q0), t0, ax);  ay = fmaf(bf16_hi(q0), t0, ay);
    }

    float2 bv = *(const float2*)(conv_b + lane * 2);
    float ox = fmaxf(fmaf(dvn, ax, bv.x), 0.f);
    float oy = fmaxf(fmaf(dvn, ay, bv.y), 0.f);
    agg2[(size_t)n * 64 + lane] = pack_bf16(ox, oy);
}

// ---------------------------------------------------------------------------
// K4: BN stats — per-feature sum/sumsq of agg2 (bf16-packed, already relu'd)
// ---------------------------------------------------------------------------
__global__ __launch_bounds__(256) void k_stats(const unsigned int* __restrict__ agg2,
                                               float* __restrict__ sums) {
    int u = threadIdx.x & 63;   // uint column -> features 2u, 2u+1
    int q = threadIdx.x >> 6;   // 0..3
    float sl = 0.f, s2l = 0.f, sh = 0.f, s2h = 0.f;
    for (int n = blockIdx.x * 4 + q; n < NN; n += gridDim.x * 4) {
        unsigned int v = agg2[(size_t)n * 64 + u];
        float a = bf16_lo(v), b = bf16_hi(v);
        sl += a;  s2l = fmaf(a, a, s2l);
        sh += b;  s2h = fmaf(b, b, s2h);
    }
    __shared__ float red[256];
    float vals[4] = {sl, sh, s2l, s2h};
    int dst[4] = {2 * u, 2 * u + 1, FH + 2 * u, FH + 2 * u + 1};
#pragma unroll
    for (int r = 0; r < 4; ++r) {
        red[threadIdx.x] = vals[r];
        __syncthreads();
        if (q == 0)
            atomicAdd(&sums[dst[r]],
                      red[u] + red[u + 64] + red[u + 128] + red[u + 192]);
        __syncthreads();
    }
}

// ---------------------------------------------------------------------------
// K5: fold BN affine into the final linear.
// ---------------------------------------------------------------------------
__global__ void k_prep(const float* __restrict__ sums,
                       const float* __restrict__ gamma,
                       const float* __restrict__ beta,
                       const float* __restrict__ lin_w,
                       const float* __restrict__ lin_b,
                       float* __restrict__ prep) {
    __shared__ float red[3 * FH];
    int f = threadIdx.x;  // 128 threads
    float mean = sums[f] * (1.0f / NN);
    float var  = sums[FH + f] * (1.0f / NN) - mean * mean;
    float inv  = rsqrtf(var + BN_EPS);
    float sc   = inv * gamma[f];
    float sh   = fmaf(-mean, sc, beta[f]);
#pragma unroll
    for (int o = 0; o < NOUT; ++o) {
        float lw = lin_w[f * NOUT + o];
        prep[f * NOUT + o] = sc * lw;
        red[o * FH + f]    = sh * lw;
    }
    __syncthreads();
    if (f < NOUT) {
        float s = lin_b[f];
        for (int i = 0; i < FH; ++i) s += red[f * FH + i];
        prep[3 * FH + f] = s;
    }
}

// ---------------------------------------------------------------------------
// K6: out[n][o] = sum_f agg[n][f] * wmod[f][o] + bias_out[o]
// ---------------------------------------------------------------------------
__global__ __launch_bounds__(256) void k_final(const unsigned int* __restrict__ agg2,
                                               const float* __restrict__ prep,
                                               float* __restrict__ out) {
    int n = blockIdx.x * 4 + (threadIdx.x >> 6);
    int lane = threadIdx.x & 63;
    int f0 = lane * 2, f1 = lane * 2 + 1;

    unsigned int v = agg2[(size_t)n * 64 + lane];
    float vx = bf16_lo(v), vy = bf16_hi(v);

    float o0 = vx * prep[f0 * NOUT + 0] + vy * prep[f1 * NOUT + 0];
    float o1 = vx * prep[f0 * NOUT + 1] + vy * prep[f1 * NOUT + 1];
    float o2 = vx * prep[f0 * NOUT + 2] + vy * prep[f1 * NOUT + 2];

#pragma unroll
    for (int off = 32; off > 0; off >>= 1) {
        o0 += __shfl_down(o0, off, 64);
        o1 += __shfl_down(o1, off, 64);
        o2 += __shfl_down(o2, off, 64);
    }
    if (lane == 0) {
        out[n * NOUT + 0] = o0 + prep[3 * FH + 0];
        out[n * NOUT + 1] = o1 + prep[3 * FH + 1];
        out[n * NOUT + 2] = o2 + prep[3 * FH + 2];
    }
}

// ---------------------------------------------------------------------------
extern "C" void kernel_launch(void* const* d_in, const int* in_sizes, int n_in,
                              void* d_out, int out_size, void* d_ws, size_t ws_size,
                              hipStream_t stream) {
    const float* x      = (const float*)d_in[0];
    const int*   ei     = (const int*)d_in[1];   // [2][NE] int32
    const float* ew     = (const float*)d_in[2];
    const float* conv_w = (const float*)d_in[3];
    const float* conv_b = (const float*)d_in[4];
    const float* gamma  = (const float*)d_in[5];
    const float* beta   = (const float*)d_in[6];
    const float* lin_w  = (const float*)d_in[7];
    const float* lin_b  = (const float*)d_in[8];
    float* out = (float*)d_out;
    float* ws  = (float*)d_ws;

    unsigned int* h2     = (unsigned int*)(ws + WS_H2);
    unsigned int* agg2   = (unsigned int*)(ws + WS_AGG2);
    unsigned int* bucket = (unsigned int*)(ws + WS_BUCKET);
    int*          cnt    = (int*)(ws + WS_CNT);
    float*        dinv   = ws + WS_DINV;
    float*        sums   = ws + WS_SUMS;
    float*        prep   = ws + WS_PREP;

    // ws is poisoned 0xAA before every launch — zero the accumulators.
    hipMemsetAsync(cnt,  0, (size_t)NN * sizeof(int), stream);
    hipMemsetAsync(sums, 0, 2 * FH * sizeof(float), stream);

    k_gemm_bucket<<<FUSED_BLKS, 256, 0, stream>>>(
        x, conv_w, h2, ei, ew, cnt, bucket);
    k_degdinv<<<NN / 4, 256, 0, stream>>>(h2, bucket, cnt, dinv);
    k_gather <<<NN / 4, 256, 0, stream>>>(h2, dinv, bucket, cnt, conv_b, agg2);
    k_stats  <<<512,    256, 0, stream>>>(agg2, sums);
    k_prep   <<<1,      FH,  0, stream>>>(sums, gamma, beta, lin_w, lin_b, prep);
    k_final  <<<NN / 4, 256, 0, stream>>>(agg2, prep, out);
}

// Round 10
// 230.502 us; speedup vs baseline: 1.0189x; 1.0189x over previous
//
#include <hip/hip_runtime.h>

// Problem constants: N=50000 nodes, E=800000 edges, IN_F=H_F=128, OUT_F=3.
#define NN   50000
#define NE   800000
#define FH   128
#define NOUT 3
#define BN_EPS 1e-5f

#define CAP  64            // bucket capacity per node; in-deg ~ Poisson(16)
#define EWS  65535.0f      // 16-bit fixed-point scale for edge weights
#define IEWS (1.0f / 65535.0f)

#define GEMM_BLKS   782    // ceil(NN/64)
#define BUCKET_BLKS 391    // ceil(NE/2048); 8 edges per thread

// Workspace layout (float-sized slots). Total ~9.75M floats = 39 MB.
#define WS_H2     0           // h packed bf16x2, uint[NN*64]
#define WS_AGG2   3200000     // relu out packed bf16x2 uint[NN*64]
#define WS_BUCKET 6400000     // uint[NN*CAP] (src<<16 | ew16)
#define WS_CNT    9600000     // int[NN] bucket counts
#define WS_DINV   9650000     // float[NN]
#define WS_SUMS   9700000     // sum[128], sumsq[128]
#define WS_PREP   9700256     // wmod[128*3], bias_out[3]

typedef __attribute__((ext_vector_type(8))) short  short8;   // 8 bf16
typedef __attribute__((ext_vector_type(4))) float  f32x4;

// round-to-nearest-even bf16 helpers
__device__ __forceinline__ unsigned int pack_bf16(float a, float b) {
    unsigned int ua = __float_as_uint(a);
    unsigned int ub = __float_as_uint(b);
    ua += 0x7fffu + ((ua >> 16) & 1u);
    ub += 0x7fffu + ((ub >> 16) & 1u);
    return (ua >> 16) | (ub & 0xffff0000u);
}
__device__ __forceinline__ unsigned short bf16_1(float a) {
    unsigned int ua = __float_as_uint(a);
    ua += 0x7fffu + ((ua >> 16) & 1u);
    return (unsigned short)(ua >> 16);
}
__device__ __forceinline__ float bf16_lo(unsigned int u) {
    return __uint_as_float(u << 16);
}
__device__ __forceinline__ float bf16_hi(unsigned int u) {
    return __uint_as_float(u & 0xffff0000u);
}

// ---------------------------------------------------------------------------
// K1: h = x @ conv_w via MFMA 16x16x32 bf16. Block = 4 waves = 64 nodes.
// B (conv_w) staged in LDS pre-swizzled into fragment order; A converted
// fp32->bf16 inline. Epilogue transposes through LDS (reusing the B buffer)
// for coalesced uint4 stores of the bf16-packed h2.
// MFMA layouts (m89-verified): A[m=lane&15][k=(lane>>4)*8+j];
// B[k=(lane>>4)*8+j][n=lane&15]; D: row m=(lane>>4)*4+reg, col n=lane&15.
// ---------------------------------------------------------------------------
__global__ __launch_bounds__(256) void k_gemm(const float* __restrict__ x,
                                              const float* __restrict__ w,
                                              unsigned int* __restrict__ h2) {
    __shared__ unsigned short swB[32 * 64 * 8];  // 32 frag-sets x 64 lanes x 8 = 32 KB
    const int tid = threadIdx.x;

    // stage B fragments: fs = kc*8 + t; lane l elem j <- w[kc*32+(l>>4)*8+j][16t+(l&15)]
#pragma unroll
    for (int it = 0; it < 8; ++it) {
        int s  = tid + it * 256;   // 0..2047 = fs*64 + l
        int l  = s & 63;
        int fs = s >> 6;
        int kc = fs >> 3, t = fs & 7;
        int n  = (l & 15) + 16 * t;
        int k0 = kc * 32 + (l >> 4) * 8;
        unsigned short* dst = &swB[s * 8];
#pragma unroll
        for (int j = 0; j < 8; ++j)
            dst[j] = bf16_1(w[(size_t)(k0 + j) * FH + n]);
    }
    __syncthreads();

    const int wv = tid >> 6, l = tid & 63;
    const int m = l & 15, q = l >> 4;
    int node = blockIdx.x * 64 + wv * 16 + m;
    if (node >= NN) node = NN - 1;               // clamp loads; stores guarded

    f32x4 acc[8];
#pragma unroll
    for (int t = 0; t < 8; ++t) acc[t] = (f32x4){0.f, 0.f, 0.f, 0.f};

#pragma unroll
    for (int kc = 0; kc < 4; ++kc) {
        const float* xr = x + (size_t)node * FH + kc * 32 + q * 8;
        float4 a0 = *(const float4*)xr;
        float4 a1 = *(const float4*)(xr + 4);
        union { short8 s8; uint4 u4; } af;
        af.u4.x = pack_bf16(a0.x, a0.y);  af.u4.y = pack_bf16(a0.z, a0.w);
        af.u4.z = pack_bf16(a1.x, a1.y);  af.u4.w = pack_bf16(a1.z, a1.w);
#pragma unroll
        for (int t = 0; t < 8; ++t) {
            union { short8 s8; uint4 u4; } bf;
            bf.u4 = *(const uint4*)&swB[((kc * 8 + t) * 64 + l) * 8];
            acc[t] = __builtin_amdgcn_mfma_f32_16x16x32_bf16(af.s8, bf.s8, acc[t], 0, 0, 0);
        }
    }

    // epilogue: D -> LDS (reuse swB) -> coalesced global
    __syncthreads();
    unsigned short* sc = swB;  // 64 nodes x 128 feats bf16 = 16 KB
#pragma unroll
    for (int t = 0; t < 8; ++t) {
#pragma unroll
        for (int r = 0; r < 4; ++r) {
            int ml = wv * 16 + q * 4 + r;   // local node (D row)
            int f  = t * 16 + m;            // feature (D col)
            sc[ml * FH + f] = bf16_1(acc[t][r]);
        }
    }
    __syncthreads();
    const uint4* s4 = (const uint4*)sc;
#pragma unroll
    for (int i = 0; i < 4; ++i) {
        int u  = tid + i * 256;             // uint4 index; 16 per node row
        int nl = u >> 4;
        int ng = blockIdx.x * 64 + nl;
        if (ng < NN)
            *((uint4*)h2 + (size_t)ng * 16 + (u & 15)) = s4[u];
    }
}

// ---------------------------------------------------------------------------
// K2: bucket edges by destination. 8 edges/thread in separated phases
// (coalesced loads, 8 independent atomics, scattered stores).
// ---------------------------------------------------------------------------
__global__ __launch_bounds__(256) void k_bucket(const int* __restrict__ ei,
                                                const float* __restrict__ ew,
                                                int* __restrict__ cnt,
                                                unsigned int* __restrict__ bucket) {
    const int e0 = blockIdx.x * 2048 + threadIdx.x;
    int          col[8];
    unsigned int ent[8];
    int          ok[8];
#pragma unroll
    for (int k = 0; k < 8; ++k) {
        int e = e0 + k * 256;
        ok[k] = (e < NE);
        int ee = ok[k] ? e : 0;
        int row = ei[ee];
        col[k] = ei[NE + ee];
        ent[k] = ((unsigned int)row << 16) | __float2uint_rn(ew[ee] * EWS);
    }
    int slot[8];
#pragma unroll
    for (int k = 0; k < 8; ++k)
        slot[k] = ok[k] ? atomicAdd(&cnt[col[k]], 1) : 0;
#pragma unroll
    for (int k = 0; k < 8; ++k)
        if (ok[k]) bucket[(size_t)col[k] * CAP + slot[k]] = ent[k];
}

// ---------------------------------------------------------------------------
// K3: dinv[n] = rsqrt(deg_n + 1). Wave per node, lane-parallel bucket sum.
// ---------------------------------------------------------------------------
__global__ __launch_bounds__(256) void k_degdinv(const unsigned int* __restrict__ bucket,
                                                 const int* __restrict__ cnt,
                                                 float* __restrict__ dinv) {
    int n = blockIdx.x * 4 + (threadIdx.x >> 6);  // 12500 blocks exactly
    int lane = threadIdx.x & 63;
    int c = cnt[n];
    unsigned int v = (lane < c) ? (bucket[(size_t)n * CAP + lane] & 0xffffu) : 0u;
#pragma unroll
    for (int off = 32; off > 0; off >>= 1) v += __shfl_down(v, off, 64);
    if (lane == 0) {
        float deg = (float)v * IEWS;
        dinv[n] = rsqrtf(deg + 1.0f);  // +1 = self loop
    }
}

// ---------------------------------------------------------------------------
// K4: gather-aggregate. One wave per node; lane owns feature pair.
// uint4 bucket loads + 8-wide unroll => 8 outstanding h2 row loads.
// ---------------------------------------------------------------------------
__global__ __launch_bounds__(256) void k_gather(const unsigned int* __restrict__ h2,
                                                const float* __restrict__ dinv,
                                                const unsigned int* __restrict__ bucket,
                                                const int* __restrict__ cnt,
                                                const float* __restrict__ conv_b,
                                                unsigned int* __restrict__ agg2) {
    int n = blockIdx.x * 4 + (threadIdx.x >> 6);  // 12500 blocks exactly
    int lane = threadIdx.x & 63;

    float dvn = dinv[n];
    unsigned int hself = h2[(size_t)n * 64 + lane];
    float ax = bf16_lo(hself) * dvn;
    float ay = bf16_hi(hself) * dvn;

    const unsigned int* bkt = bucket + (size_t)n * CAP;
    int c = cnt[n];
    int j = 0;
    for (; j + 8 <= c; j += 8) {
        uint4 b0 = *(const uint4*)(bkt + j);
        uint4 b1 = *(const uint4*)(bkt + j + 4);
        unsigned int u[8] = {b0.x, b0.y, b0.z, b0.w, b1.x, b1.y, b1.z, b1.w};
        float t[8];
        unsigned int q[8];
#pragma unroll
        for (int r = 0; r < 8; ++r) {
            int s = u[r] >> 16;
            t[r] = dinv[s] * (float)(u[r] & 0xffffu) * IEWS;
            q[r] = h2[(size_t)s * 64 + lane];
        }
#pragma unroll
        for (int r = 0; r < 8; ++r) {
            ax = fmaf(bf16_lo(q[r]), t[r], ax);
            ay = fmaf(bf16_hi(q[r]), t[r], ay);
        }
    }
    if (j + 4 <= c) {
        uint4 b0 = *(const uint4*)(bkt + j);
        unsigned int u[4] = {b0.x, b0.y, b0.z, b0.w};
#pragma unroll
        for (int r = 0; r < 4; ++r) {
            int s = u[r] >> 16;
            float t = dinv[s] * (float)(u[r] & 0xffffu) * IEWS;
            unsigned int q = h2[(size_t)s * 64 + lane];
            ax = fmaf(bf16_lo(q), t, ax);
            ay = fmaf(bf16_hi(q), t, ay);
        }
        j += 4;
    }
    for (; j < c; ++j) {
        unsigned int u0 = bkt[j];
        int s0 = u0 >> 16;
        float t0 = dinv[s0] * (float)(u0 & 0xffffu) * IEWS;
        unsigned int q0 = h2[(size_t)s0 * 64 + lane];
        ax = fmaf(bf16_lo(q0), t0, ax);  ay = fmaf(bf16_hi(q0), t0, ay);
    }

    float2 bv = *(const float2*)(conv_b + lane * 2);
    float ox = fmaxf(fmaf(dvn, ax, bv.x), 0.f);
    float oy = fmaxf(fmaf(dvn, ay, bv.y), 0.f);
    agg2[(size_t)n * 64 + lane] = pack_bf16(ox, oy);
}

// ---------------------------------------------------------------------------
// K5: BN stats — per-feature sum/sumsq of agg2 (bf16-packed, already relu'd)
// ---------------------------------------------------------------------------
__global__ __launch_bounds__(256) void k_stats(const unsigned int* __restrict__ agg2,
                                               float* __restrict__ sums) {
    int u = threadIdx.x & 63;   // uint column -> features 2u, 2u+1
    int q = threadIdx.x >> 6;   // 0..3
    float sl = 0.f, s2l = 0.f, sh = 0.f, s2h = 0.f;
    for (int n = blockIdx.x * 4 + q; n < NN; n += gridDim.x * 4) {
        unsigned int v = agg2[(size_t)n * 64 + u];
        float a = bf16_lo(v), b = bf16_hi(v);
        sl += a;  s2l = fmaf(a, a, s2l);
        sh += b;  s2h = fmaf(b, b, s2h);
    }
    __shared__ float red[256];
    float vals[4] = {sl, sh, s2l, s2h};
    int dst[4] = {2 * u, 2 * u + 1, FH + 2 * u, FH + 2 * u + 1};
#pragma unroll
    for (int r = 0; r < 4; ++r) {
        red[threadIdx.x] = vals[r];
        __syncthreads();
        if (q == 0)
            atomicAdd(&sums[dst[r]],
                      red[u] + red[u + 64] + red[u + 128] + red[u + 192]);
        __syncthreads();
    }
}

// ---------------------------------------------------------------------------
// K6: fold BN affine into the final linear.
// ---------------------------------------------------------------------------
__global__ void k_prep(const float* __restrict__ sums,
                       const float* __restrict__ gamma,
                       const float* __restrict__ beta,
                       const float* __restrict__ lin_w,
                       const float* __restrict__ lin_b,
                       float* __restrict__ prep) {
    __shared__ float red[3 * FH];
    int f = threadIdx.x;  // 128 threads
    float mean = sums[f] * (1.0f / NN);
    float var  = sums[FH + f] * (1.0f / NN) - mean * mean;
    float inv  = rsqrtf(var + BN_EPS);
    float sc   = inv * gamma[f];
    float sh   = fmaf(-mean, sc, beta[f]);
#pragma unroll
    for (int o = 0; o < NOUT; ++o) {
        float lw = lin_w[f * NOUT + o];
        prep[f * NOUT + o] = sc * lw;
        red[o * FH + f]    = sh * lw;
    }
    __syncthreads();
    if (f < NOUT) {
        float s = lin_b[f];
        for (int i = 0; i < FH; ++i) s += red[f * FH + i];
        prep[3 * FH + f] = s;
    }
}

// ---------------------------------------------------------------------------
// K7: out[n][o] = sum_f agg[n][f] * wmod[f][o] + bias_out[o]
// ---------------------------------------------------------------------------
__global__ __launch_bounds__(256) void k_final(const unsigned int* __restrict__ agg2,
                                               const float* __restrict__ prep,
                                               float* __restrict__ out) {
    int n = blockIdx.x * 4 + (threadIdx.x >> 6);
    int lane = threadIdx.x & 63;
    int f0 = lane * 2, f1 = lane * 2 + 1;

    unsigned int v = agg2[(size_t)n * 64 + lane];
    float vx = bf16_lo(v), vy = bf16_hi(v);

    float o0 = vx * prep[f0 * NOUT + 0] + vy * prep[f1 * NOUT + 0];
    float o1 = vx * prep[f0 * NOUT + 1] + vy * prep[f1 * NOUT + 1];
    float o2 = vx * prep[f0 * NOUT + 2] + vy * prep[f1 * NOUT + 2];

#pragma unroll
    for (int off = 32; off > 0; off >>= 1) {
        o0 += __shfl_down(o0, off, 64);
        o1 += __shfl_down(o1, off, 64);
        o2 += __shfl_down(o2, off, 64);
    }
    if (lane == 0) {
        out[n * NOUT + 0] = o0 + prep[3 * FH + 0];
        out[n * NOUT + 1] = o1 + prep[3 * FH + 1];
        out[n * NOUT + 2] = o2 + prep[3 * FH + 2];
    }
}

// ---------------------------------------------------------------------------
extern "C" void kernel_launch(void* const* d_in, const int* in_sizes, int n_in,
                              void* d_out, int out_size, void* d_ws, size_t ws_size,
                              hipStream_t stream) {
    const float* x      = (const float*)d_in[0];
    const int*   ei     = (const int*)d_in[1];   // [2][NE] int32
    const float* ew     = (const float*)d_in[2];
    const float* conv_w = (const float*)d_in[3];
    const float* conv_b = (const float*)d_in[4];
    const float* gamma  = (const float*)d_in[5];
    const float* beta   = (const float*)d_in[6];
    const float* lin_w  = (const float*)d_in[7];
    const float* lin_b  = (const float*)d_in[8];
    float* out = (float*)d_out;
    float* ws  = (float*)d_ws;

    unsigned int* h2     = (unsigned int*)(ws + WS_H2);
    unsigned int* agg2   = (unsigned int*)(ws + WS_AGG2);
    unsigned int* bucket = (unsigned int*)(ws + WS_BUCKET);
    int*          cnt    = (int*)(ws + WS_CNT);
    float*        dinv   = ws + WS_DINV;
    float*        sums   = ws + WS_SUMS;
    float*        prep   = ws + WS_PREP;

    // ws is poisoned 0xAA before every launch — zero the accumulators.
    hipMemsetAsync(cnt,  0, (size_t)NN * sizeof(int), stream);
    hipMemsetAsync(sums, 0, 2 * FH * sizeof(float), stream);

    k_bucket <<<BUCKET_BLKS, 256, 0, stream>>>(ei, ew, cnt, bucket);
    k_gemm   <<<GEMM_BLKS,   256, 0, stream>>>(x, conv_w, h2);
    k_degdinv<<<NN / 4,      256, 0, stream>>>(bucket, cnt, dinv);
    k_gather <<<NN / 4,      256, 0, stream>>>(h2, dinv, bucket, cnt, conv_b, agg2);
    k_stats  <<<512,         256, 0, stream>>>(agg2, sums);
    k_prep   <<<1,           FH,  0, stream>>>(sums, gamma, beta, lin_w, lin_b, prep);
    k_final  <<<NN / 4,      256, 0, stream>>>(agg2, prep, out);
}